// Round 4
// baseline (394.290 us; speedup 1.0000x reference)
//
#include <hip/hip_runtime.h>
#include <cstdint>

// ---------------- problem constants ----------------
constexpr int RS  = 48;    // sigma ranks
constexpr int RC  = 144;   // feature ranks
constexpr int PP  = 27;    // feats dim
constexpr int NV  = 128;   // voxels per axis
constexpr int CHN = 128;   // MLP hidden

// ---------------- ws layout ----------------
// f32 (lo,delta) pair tables, float offsets:
constexpr int SIGP  = 3 * NV * 64;    // 24576 pairs  [3][128 vox][64 ranks]
constexpr int FEATP = 3 * NV * 160;   // 61440 pairs  [3][128 vox][160 ranks]
constexpr int NPAIR = SIGP + FEATP;   // 86016 pairs = 172032 floats (688KB)
// bf16 fragment region, short offsets from frag base (= ws + 2*NPAIR floats):
constexpr int FR_B  = 0;              // B frags  [5][2][64][8] = 5120
constexpr int FR_W1 = 5120;           // W1 frags [4][8][64][8] = 16384
constexpr int FR_W2 = 21504;          // W2 frags               = 16384
constexpr int FR_W3 = 37888;          // W3 frags [4][64][8]    = 2048
constexpr int FR_TOT = 39936;         // ~78KB  -> total ws ~750KB

typedef __attribute__((ext_vector_type(8))) short short8;
typedef __attribute__((ext_vector_type(4))) float f32x4;
typedef __attribute__((ext_vector_type(2))) unsigned int u32x2;
typedef __attribute__((ext_vector_type(4))) unsigned int u32x4;

__device__ __forceinline__ short f2bf(float f) {          // RNE (prep only)
    unsigned int u = __builtin_bit_cast(unsigned int, f);
    u += 0x7fffu + ((u >> 16) & 1u);
    return (short)(u >> 16);
}
// pack two floats -> 2 bf16 in one dword (v_cvt_pk_bf16_f32)
__device__ __forceinline__ unsigned int pk2bf(float a, float b) {
    unsigned short ua = __builtin_bit_cast(unsigned short, (__bf16)a);
    unsigned short ub = __builtin_bit_cast(unsigned short, (__bf16)b);
    return (unsigned int)ua | ((unsigned int)ub << 16);
}

// ---------------- prep 1: f32 (lo, delta) pair tables ----------------
__global__ void prep_tables(const float* __restrict__ sigma, const float* __restrict__ feature,
                            float* __restrict__ wf) {
    int idx = blockIdx.x * 256 + threadIdx.x;
    if (idx >= NPAIR) return;
    float lo = 0.f, hi = 0.f;
    if (idx < SIGP) {
        int a = idx / 8192, t = idx % 8192;
        int v = t / 64, r = t % 64;
        if (r < RS) {
            lo = sigma[(a * RS + r) * NV + v];
            hi = sigma[(a * RS + r) * NV + min(v + 1, NV - 1)];
        }
    } else {
        int j = idx - SIGP;
        int a = j / 20480, t = j % 20480;
        int v = t / 160, r = t % 160;
        if (r < RC) {
            lo = feature[(a * RC + r) * NV + v];
            hi = feature[(a * RC + r) * NV + min(v + 1, NV - 1)];
        }
    }
    wf[2 * idx]     = lo;
    wf[2 * idx + 1] = hi - lo;    // lerp = fmaf(delta, w, lo)
}

// ---------------- prep 2: bf16 fragment-layout weights ----------------
__global__ void prep_frags(const float* __restrict__ Bm, const float* __restrict__ W1,
                           const float* __restrict__ W2, const float* __restrict__ W3,
                           short* __restrict__ fr) {
    int idx = blockIdx.x * 256 + threadIdx.x;
    if (idx >= FR_TOT) return;
    float val = 0.f;
    if (idx < FR_W1) {                          // B frags
        int j = idx - FR_B;
        int frag = j >> 9, li = (j >> 3) & 63, e = j & 7;
        int kt = frag >> 1, nt = frag & 1;
        int k = kt * 32 + (li >> 4) * 8 + e;
        int n = nt * 16 + (li & 15);
        val = (k < RC && n < PP) ? Bm[k * PP + n] : 0.f;
    } else if (idx < FR_W2) {                   // W1 frags, permuted rows
        int j = idx - FR_W1;
        int frag = j >> 9, li = (j >> 3) & 63, e = j & 7;
        int kt = frag >> 3, nt = frag & 7;
        int kn = kt * 32 + (li >> 4) * 8 + e;   // k in interleaved-encode order
        int n = nt * 16 + (li & 15);
        if (kn < 120) {
            int ko;
            if (kn < 108) { ko = (kn & 3) * PP + (kn >> 2); }            // feats: l*27 + c
            else { int t2 = kn - 108; ko = 108 + (t2 & 3) * 3 + (t2 >> 2); } // dirs
            val = W1[ko * CHN + n];
        }
    } else if (idx < FR_W3) {                   // W2 frags
        int j = idx - FR_W2;
        int frag = j >> 9, li = (j >> 3) & 63, e = j & 7;
        int kt = frag >> 3, nt = frag & 7;
        int k = kt * 32 + (li >> 4) * 8 + e;
        int n = nt * 16 + (li & 15);
        val = W2[k * CHN + n];
    } else {                                    // W3 frags
        int j = idx - FR_W3;
        int frag = j >> 9, li = (j >> 3) & 63, e = j & 7;
        int kt = frag;
        int k = kt * 32 + (li >> 4) * 8 + e;
        int n = li & 15;
        val = (n < 3) ? W3[k * 3 + n] : 0.f;
    }
    fr[idx] = f2bf(val);
}

// lerp 8 ranks from (lo,delta) pairs: 1 fma/rank (+ product mul)
__device__ __forceinline__ void lerpd8(const float* rl, float w, float* pr, bool first) {
#pragma unroll
    for (int h = 0; h < 4; ++h) {
        f32x4 v = *(const f32x4*)(rl + h * 4);   // lo0,d0,lo1,d1
        float s0 = fmaf(v[1], w, v[0]);
        float s1 = fmaf(v[3], w, v[2]);
        if (first) { pr[2 * h] = s0; pr[2 * h + 1] = s1; }
        else       { pr[2 * h] *= s0; pr[2 * h + 1] *= s1; }
    }
}

// ---------------- main fused kernel: 4 waves/block, 16 points per wave ----------------
// LDS/block: 4 x 4KB X = 16KB -> 10 blocks/CU by LDS; VGPR cap via (256,6) ~84
// -> 24 waves/CU (75%). Enough regs to pipeline the gathers (R3's VGPR=32 choke).
__global__ __launch_bounds__(256, 6)
void tensorf_main(const float* __restrict__ xyz, const float* __restrict__ dird,
                  const float* __restrict__ voxel,
                  const float* __restrict__ b1, const float* __restrict__ b2,
                  const float* __restrict__ b3,
                  const float* __restrict__ wf, const short* __restrict__ fr,
                  float* __restrict__ out, int Np) {
    __shared__ char X[4 * 16 * 256];  // per-wave 16 pts x 128 bf16, XOR-swizzled

    const int tid = threadIdx.x;
    const int wid = tid >> 6;
    const int lane = tid & 63;
    const int quad = lane >> 4, lane16 = lane & 15;
    const int wavebase = blockIdx.x * 64 + wid * 16;
    char* Xw = X + wid * 16 * 256;

    const float* SIGF  = wf;
    const float* FEATF = wf + 2 * SIGP;
    const short* BFr   = fr + FR_B;

    // ---------------- phase A: one pass of 16 points ----------------
    {
        const int p = wavebase + lane16;

        int ipb[3]; float we[3];
#pragma unroll
        for (int a = 0; a < 3; ++a) {
            const float* vax = voxel + a * NV;   // 1.5KB, L1-resident
            float x = xyz[p * 3 + a];
            int ind = (int)ceilf(x * 127.f);
            ind = min(max(ind, 0), 128);
            while (ind > 0 && vax[ind - 1] >= x) --ind;   // searchsorted-left fixup
            while (ind < 128 && vax[ind] < x) ++ind;
            int il = min(max(ind - 1, 0), 127);
            int ir = min(ind, 127);
            float vl = vax[il], vr = vax[ir];
            float w = (x - vl) / (vr - vl + 1e-6f);
            we[a] = (il == 127) ? 1.f : w;       // il==ir==127 edge
            ipb[a] = min(il, 126);
        }

        // ---- sigma ----
        float sig = 0.f;
#pragma unroll
        for (int kt = 0; kt < 2; ++kt) {
            float pr[8];
#pragma unroll
            for (int a = 0; a < 3; ++a)
                lerpd8(SIGF + ((a * NV + ipb[a]) * 64 + kt * 32 + quad * 8) * 2, we[a], pr, a == 0);
#pragma unroll
            for (int j = 0; j < 8; ++j) sig += pr[j];
        }
        sig += __shfl_xor(sig, 16);
        sig += __shfl_xor(sig, 32);
        if (lane < 16) out[p] = log1pf(expf(sig - 5.f));   // softplus(sig + bias)

        // ---- feats = fprod @ B via MFMA ----
        f32x4 acc0 = {0.f, 0.f, 0.f, 0.f}, acc1 = {0.f, 0.f, 0.f, 0.f};
#pragma unroll
        for (int kt = 0; kt < 5; ++kt) {
            float pr[8];
#pragma unroll
            for (int a = 0; a < 3; ++a)
                lerpd8(FEATF + ((a * NV + ipb[a]) * 160 + kt * 32 + quad * 8) * 2, we[a], pr, a == 0);
            u32x4 uu;
#pragma unroll
            for (int d = 0; d < 4; ++d) uu[d] = pk2bf(pr[2 * d], pr[2 * d + 1]);
            short8 af = __builtin_bit_cast(short8, uu);
            short8 bf0 = *(const short8*)(BFr + ((kt * 2 + 0) * 64 + lane) * 8);
            short8 bf1 = *(const short8*)(BFr + ((kt * 2 + 1) * 64 + lane) * 8);
            acc0 = __builtin_amdgcn_mfma_f32_16x16x32_bf16(af, bf0, acc0, 0, 0, 0);
            acc1 = __builtin_amdgcn_mfma_f32_16x16x32_bf16(af, bf1, acc1, 0, 0, 0);
        }

        // ---- encode feats -> X (double-angle for the l=1 band) ----
#pragma unroll
        for (int nt = 0; nt < 2; ++nt) {
            int c = nt * 16 + lane16;
            f32x4 A = nt ? acc1 : acc0;
            if (c < PP) {
#pragma unroll
                for (int j = 0; j < 4; ++j) {
                    int row = quad * 4 + j;              // D-frag row
                    float f = A[j];
                    float s1 = __sinf(f), c1 = __cosf(f);
                    float s2 = 2.f * s1 * c1;            // sin 2f
                    float c2 = fmaf(-2.f * s1, s1, 1.f); // cos 2f
                    unsigned int w0 = pk2bf(s1, c1);
                    unsigned int w1 = pk2bf(s2, c2);
                    int byte = c * 8;
                    int chunk = byte >> 4, off = byte & 15;
                    *(u32x2*)(Xw + row * 256 + ((chunk ^ (row & 7)) << 4) + off) = u32x2{w0, w1};
                }
            }
        }
        // ---- dirs encode + zero-pad cols 120..127 ----
        {
            int row = lane16;
            if (quad < 3) {
                float d = dird[p * 3 + quad];
                float s1 = __sinf(d), c1 = __cosf(d);
                float s2 = 2.f * s1 * c1;
                float c2 = fmaf(-2.f * s1, s1, 1.f);
                unsigned int w0 = pk2bf(s1, c1);
                unsigned int w1 = pk2bf(s2, c2);
                int byte = 216 + 8 * quad;
                int chunk = byte >> 4, off = byte & 15;
                *(u32x2*)(Xw + row * 256 + ((chunk ^ (row & 7)) << 4) + off) = u32x2{w0, w1};
            } else {
                int addr = row * 256 + ((15 ^ (row & 7)) << 4);
                *(u32x4*)(Xw + addr) = u32x4{0u, 0u, 0u, 0u};
            }
        }
    }
    __syncthreads();

    // ---------------- phase B: per-wave MLP, M=16 (1 tile) ----------------
    const short* W1F = fr + FR_W1;
    const short* W2F = fr + FR_W2;
    const short* W3F = fr + FR_W3;

#pragma unroll 1
    for (int layer = 0; layer < 2; ++layer) {
        const short* WF = layer ? W2F : W1F;
        const float* bb = layer ? b2 : b1;

        short8 af[4];
#pragma unroll
        for (int kt = 0; kt < 4; ++kt) {
            int row = lane16;
            int chunk = kt * 4 + quad;
            af[kt] = *(const short8*)(Xw + row * 256 + ((chunk ^ (row & 7)) << 4));
        }

#pragma unroll 1
        for (int nt = 0; nt < 8; ++nt) {
            short8 wfv[4];
#pragma unroll
            for (int kt = 0; kt < 4; ++kt)
                wfv[kt] = *(const short8*)(WF + ((kt * 8 + nt) * 64 + lane) * 8);
            f32x4 acc = {0.f, 0.f, 0.f, 0.f};
#pragma unroll
            for (int kt = 0; kt < 4; ++kt)
                acc = __builtin_amdgcn_mfma_f32_16x16x32_bf16(af[kt], wfv[kt], acc, 0, 0, 0);

            float bvv = bb[nt * 16 + lane16];
#pragma unroll
            for (int j = 0; j < 4; ++j) {
                float v = acc[j] + bvv;
                v = fmaxf(v, 0.01f * v);                // leaky relu
                int row = quad * 4 + j;
                int byte = (nt * 16 + lane16) * 2;
                int chunk = byte >> 4, off = byte & 15;
                *(short*)(Xw + row * 256 + ((chunk ^ (row & 7)) << 4) + off) =
                    (short)__builtin_bit_cast(unsigned short, (__bf16)v);
            }
        }
        __syncthreads();
    }

    // ---- layer 3: 128 -> 3 (+sigmoid) ----
    {
        short8 af[4];
#pragma unroll
        for (int kt = 0; kt < 4; ++kt) {
            int row = lane16;
            int chunk = kt * 4 + quad;
            af[kt] = *(const short8*)(Xw + row * 256 + ((chunk ^ (row & 7)) << 4));
        }
        short8 wf3[4];
#pragma unroll
        for (int kt = 0; kt < 4; ++kt)
            wf3[kt] = *(const short8*)(W3F + (kt * 64 + lane) * 8);

        f32x4 acc3 = {0.f, 0.f, 0.f, 0.f};
#pragma unroll
        for (int kt = 0; kt < 4; ++kt)
            acc3 = __builtin_amdgcn_mfma_f32_16x16x32_bf16(af[kt], wf3[kt], acc3, 0, 0, 0);

        if (lane16 < 3) {
            float bvv = b3[lane16];
#pragma unroll
            for (int j = 0; j < 4; ++j) {
                float v = acc3[j] + bvv;
                float r = 1.f / (1.f + expf(-v));       // sigmoid
                int row = quad * 4 + j;
                out[Np + (wavebase + row) * 3 + lane16] = r;
            }
        }
    }
}

// ---------------- launch ----------------
extern "C" void kernel_launch(void* const* d_in, const int* in_sizes, int n_in,
                              void* d_out, int out_size, void* d_ws, size_t ws_size,
                              hipStream_t stream) {
    (void)n_in; (void)out_size; (void)ws_size;  // ws need: ~750KB
    const float* xyz      = (const float*)d_in[0];
    const float* dird     = (const float*)d_in[1];
    const float* voxel    = (const float*)d_in[2];
    const float* sigma    = (const float*)d_in[3];
    const float* feature  = (const float*)d_in[4];
    const float* Bm       = (const float*)d_in[5];
    const float* W1       = (const float*)d_in[6];
    const float* b1       = (const float*)d_in[7];
    const float* W2       = (const float*)d_in[8];
    const float* b2       = (const float*)d_in[9];
    const float* W3       = (const float*)d_in[10];
    const float* b3       = (const float*)d_in[11];
    float* out = (float*)d_out;
    float* wf  = (float*)d_ws;
    short* frg = (short*)d_ws + 2 * 2 * NPAIR;   // frag region after 172032 floats

    const int Np = in_sizes[0] / 3;   // 524288

    prep_tables<<<(NPAIR + 255) / 256, 256, 0, stream>>>(sigma, feature, wf);
    prep_frags<<<(FR_TOT + 255) / 256, 256, 0, stream>>>(Bm, W1, W2, W3, frg);
    tensorf_main<<<Np / 64, 256, 0, stream>>>(xyz, dird, voxel, b1, b2, b3, wf, frg, out, Np);
}

// Round 5
// 215.143 us; speedup vs baseline: 1.8327x; 1.8327x over previous
//
#include <hip/hip_runtime.h>
#include <cstdint>

// ---------------- problem constants ----------------
constexpr int RS  = 48;    // sigma ranks
constexpr int RC  = 144;   // feature ranks
constexpr int PP  = 27;    // feats dim
constexpr int NV  = 128;   // voxels per axis
constexpr int CHN = 128;   // MLP hidden

// ---------------- ws layout ----------------
// f16 (lo,delta) packed pair tables, dword offsets:
constexpr int SIG_D  = 3 * NV * 64;    // 24576 dwords [3][128 vox][64 ranks]
constexpr int FEAT_D = 3 * NV * 160;   // 61440 dwords [3][128 vox][160 ranks]
constexpr int NPAIR  = SIG_D + FEAT_D; // 86016 dwords = 344KB
// bf16 fragment region, short offsets from frag base (= ws + NPAIR dwords):
constexpr int FR_B  = 0;              // B frags  [5][2][64][8] = 5120
constexpr int FR_W1 = 5120;           // W1 frags [4][8][64][8] = 16384
constexpr int FR_W2 = 21504;          // W2 frags               = 16384
constexpr int FR_W3 = 37888;          // W3 frags [4][64][8]    = 2048
constexpr int FR_TOT = 39936;         // ~78KB -> total ws ~424KB

typedef __attribute__((ext_vector_type(8))) short short8;
typedef __attribute__((ext_vector_type(4))) float f32x4;
typedef __attribute__((ext_vector_type(2))) unsigned int u32x2;
typedef __attribute__((ext_vector_type(4))) unsigned int u32x4;
typedef _Float16 h2 __attribute__((ext_vector_type(2)));

__device__ __forceinline__ short f2bf(float f) {          // RNE (prep only)
    unsigned int u = __builtin_bit_cast(unsigned int, f);
    u += 0x7fffu + ((u >> 16) & 1u);
    return (short)(u >> 16);
}
// pack two floats -> 2 bf16 in one dword (v_cvt_pk_bf16_f32)
__device__ __forceinline__ unsigned int pk2bf(float a, float b) {
    unsigned short ua = __builtin_bit_cast(unsigned short, (__bf16)a);
    unsigned short ub = __builtin_bit_cast(unsigned short, (__bf16)b);
    return (unsigned int)ua | ((unsigned int)ub << 16);
}
// lerp via v_dot2_f32_f16: (lo,delta) . (1,w) + 0
__device__ __forceinline__ float dot2lerp(unsigned int lodelta, h2 wv) {
#if __has_builtin(__builtin_amdgcn_fdot2)
    return __builtin_amdgcn_fdot2(__builtin_bit_cast(h2, lodelta), wv, 0.f, false);
#else
    h2 a = __builtin_bit_cast(h2, lodelta);
    return (float)a.x * (float)wv.x + (float)a.y * (float)wv.y;
#endif
}

// ---------------- prep 1: f16 (lo, delta) packed tables ----------------
__global__ void prep_tables(const float* __restrict__ sigma, const float* __restrict__ feature,
                            unsigned int* __restrict__ wt) {
    int idx = blockIdx.x * 256 + threadIdx.x;
    if (idx >= NPAIR) return;
    float lo = 0.f, hi = 0.f;
    if (idx < SIG_D) {
        int a = idx / 8192, t = idx % 8192;
        int v = t / 64, r = t % 64;
        if (r < RS) {
            lo = sigma[(a * RS + r) * NV + v];
            hi = sigma[(a * RS + r) * NV + min(v + 1, NV - 1)];
        }
    } else {
        int j = idx - SIG_D;
        int a = j / 20480, t = j % 20480;
        int v = t / 160, r = t % 160;
        if (r < RC) {
            lo = feature[(a * RC + r) * NV + v];
            hi = feature[(a * RC + r) * NV + min(v + 1, NV - 1)];
        }
    }
    _Float16 lh = (_Float16)lo;
    _Float16 dh = (_Float16)(hi - lo);
    wt[idx] = (unsigned int)__builtin_bit_cast(unsigned short, lh) |
              ((unsigned int)__builtin_bit_cast(unsigned short, dh) << 16);
}

// ---------------- prep 2: bf16 fragment-layout weights ----------------
__global__ void prep_frags(const float* __restrict__ Bm, const float* __restrict__ W1,
                           const float* __restrict__ W2, const float* __restrict__ W3,
                           short* __restrict__ fr) {
    int idx = blockIdx.x * 256 + threadIdx.x;
    if (idx >= FR_TOT) return;
    float val = 0.f;
    if (idx < FR_W1) {                          // B frags
        int j = idx - FR_B;
        int frag = j >> 9, li = (j >> 3) & 63, e = j & 7;
        int kt = frag >> 1, nt = frag & 1;
        int k = kt * 32 + (li >> 4) * 8 + e;
        int n = nt * 16 + (li & 15);
        val = (k < RC && n < PP) ? Bm[k * PP + n] : 0.f;
    } else if (idx < FR_W2) {                   // W1 frags, permuted rows
        int j = idx - FR_W1;
        int frag = j >> 9, li = (j >> 3) & 63, e = j & 7;
        int kt = frag >> 3, nt = frag & 7;
        int kn = kt * 32 + (li >> 4) * 8 + e;   // k in interleaved-encode order
        int n = nt * 16 + (li & 15);
        if (kn < 120) {
            int ko;
            if (kn < 108) { ko = (kn & 3) * PP + (kn >> 2); }            // feats: l*27 + c
            else { int t2 = kn - 108; ko = 108 + (t2 & 3) * 3 + (t2 >> 2); } // dirs
            val = W1[ko * CHN + n];
        }
    } else if (idx < FR_W3) {                   // W2 frags
        int j = idx - FR_W2;
        int frag = j >> 9, li = (j >> 3) & 63, e = j & 7;
        int kt = frag >> 3, nt = frag & 7;
        int k = kt * 32 + (li >> 4) * 8 + e;
        int n = nt * 16 + (li & 15);
        val = W2[k * CHN + n];
    } else {                                    // W3 frags
        int j = idx - FR_W3;
        int frag = j >> 9, li = (j >> 3) & 63, e = j & 7;
        int kt = frag;
        int k = kt * 32 + (li >> 4) * 8 + e;
        int n = li & 15;
        val = (n < 3) ? W3[k * 3 + n] : 0.f;
    }
    fr[idx] = f2bf(val);
}

// lerp 8 ranks (8 packed dwords = 32B contiguous): 1 fdot2/rank
__device__ __forceinline__ void lerpf8(const unsigned int* rl, h2 wv, float* pr, bool first) {
    u32x4 A  = *(const u32x4*)rl;        // ranks 0..3
    u32x4 Bv = *(const u32x4*)(rl + 4);  // ranks 4..7
#pragma unroll
    for (int d = 0; d < 4; ++d) {
        float s0 = dot2lerp(A[d], wv);
        float s1 = dot2lerp(Bv[d], wv);
        if (first) { pr[d] = s0; pr[4 + d] = s1; }
        else       { pr[d] *= s0; pr[4 + d] *= s1; }
    }
}

// ---------------- main fused kernel: 2 waves/block, 32 points per wave ----------------
// (R2 geometry — best measured. LDS: 2x8KB X + 1.5KB voxs = 17.5KB -> 9 blocks/CU.)
__global__ __launch_bounds__(128, 4)
void tensorf_main(const float* __restrict__ xyz, const float* __restrict__ dird,
                  const float* __restrict__ voxel,
                  const float* __restrict__ b1, const float* __restrict__ b2,
                  const float* __restrict__ b3,
                  const unsigned int* __restrict__ wt, const short* __restrict__ fr,
                  float* __restrict__ out, int Np) {
    __shared__ float voxs[3 * NV];
    __shared__ char  X[2 * 32 * 256];  // per-wave 32 pts x 128 bf16, XOR-swizzled

    const int tid = threadIdx.x;
    const int wid = tid >> 6;
    const int lane = tid & 63;
    const int quad = lane >> 4, lane16 = lane & 15;
    const int wavebase = blockIdx.x * 64 + wid * 32;
    char* Xw = X + wid * 32 * 256;

    for (int i = tid; i < 3 * NV; i += 128) voxs[i] = voxel[i];
    __syncthreads();

    const unsigned int* SIGU  = wt;
    const unsigned int* FEATU = wt + SIG_D;
    const short* BFr = fr + FR_B;

    // ---------------- phase A: 2 passes x 16 points ----------------
#pragma unroll 1
    for (int q = 0; q < 2; ++q) {
        const int rowbase = q * 16;
        const int p = wavebase + rowbase + lane16;

        int ipb[3]; h2 wv[3];
#pragma unroll
        for (int a = 0; a < 3; ++a) {
            float x = xyz[p * 3 + a];
            int ind = (int)ceilf(x * 127.f);
            ind = min(max(ind, 0), 128);
            while (ind > 0 && voxs[a * NV + ind - 1] >= x) --ind;   // searchsorted-left fixup
            while (ind < 128 && voxs[a * NV + ind] < x) ++ind;
            int il = min(max(ind - 1, 0), 127);
            int ir = min(ind, 127);
            float vl = voxs[a * NV + il], vr = voxs[a * NV + ir];
            float w = (x - vl) / (vr - vl + 1e-6f);
            w = (il == 127) ? 1.f : w;           // il==ir==127 edge
            ipb[a] = min(il, 126);
            wv[a] = h2{(_Float16)1.0f, (_Float16)w};
        }

        // ---- sigma: 1 fdot2 per rank-lerp ----
        float sig = 0.f;
#pragma unroll
        for (int kt = 0; kt < 2; ++kt) {
            float pr[8];
#pragma unroll
            for (int a = 0; a < 3; ++a)
                lerpf8(SIGU + (a * NV + ipb[a]) * 64 + kt * 32 + quad * 8, wv[a], pr, a == 0);
#pragma unroll
            for (int j = 0; j < 8; ++j) sig += pr[j];
        }
        sig += __shfl_xor(sig, 16);
        sig += __shfl_xor(sig, 32);
        if (lane < 16) out[p] = log1pf(expf(sig - 5.f));   // softplus(sig + bias)

        // ---- feats = fprod @ B via MFMA ----
        f32x4 acc0 = {0.f, 0.f, 0.f, 0.f}, acc1 = {0.f, 0.f, 0.f, 0.f};
#pragma unroll
        for (int kt = 0; kt < 5; ++kt) {
            float pr[8];
#pragma unroll
            for (int a = 0; a < 3; ++a)
                lerpf8(FEATU + (a * NV + ipb[a]) * 160 + kt * 32 + quad * 8, wv[a], pr, a == 0);
            u32x4 uu;
#pragma unroll
            for (int d = 0; d < 4; ++d) uu[d] = pk2bf(pr[2 * d], pr[2 * d + 1]);
            short8 af = __builtin_bit_cast(short8, uu);
            short8 bf0 = *(const short8*)(BFr + ((kt * 2 + 0) * 64 + lane) * 8);
            short8 bf1 = *(const short8*)(BFr + ((kt * 2 + 1) * 64 + lane) * 8);
            acc0 = __builtin_amdgcn_mfma_f32_16x16x32_bf16(af, bf0, acc0, 0, 0, 0);
            acc1 = __builtin_amdgcn_mfma_f32_16x16x32_bf16(af, bf1, acc1, 0, 0, 0);
        }

        // ---- encode feats -> X (double-angle for the l=1 band) ----
#pragma unroll
        for (int nt = 0; nt < 2; ++nt) {
            int c = nt * 16 + lane16;
            f32x4 A = nt ? acc1 : acc0;
            if (c < PP) {
#pragma unroll
                for (int j = 0; j < 4; ++j) {
                    int row = rowbase + quad * 4 + j;    // D-frag row
                    float f = A[j];
                    float s1 = __sinf(f), c1 = __cosf(f);
                    float s2 = 2.f * s1 * c1;            // sin 2f
                    float c2 = fmaf(-2.f * s1, s1, 1.f); // cos 2f
                    unsigned int w0 = pk2bf(s1, c1);
                    unsigned int w1 = pk2bf(s2, c2);
                    int byte = c * 8;
                    int chunk = byte >> 4, off = byte & 15;
                    *(u32x2*)(Xw + row * 256 + ((chunk ^ (row & 7)) << 4) + off) = u32x2{w0, w1};
                }
            }
        }
        // ---- dirs encode + zero-pad cols 120..127 ----
        {
            int row = rowbase + lane16;
            if (quad < 3) {
                float d = dird[p * 3 + quad];
                float s1 = __sinf(d), c1 = __cosf(d);
                float s2 = 2.f * s1 * c1;
                float c2 = fmaf(-2.f * s1, s1, 1.f);
                unsigned int w0 = pk2bf(s1, c1);
                unsigned int w1 = pk2bf(s2, c2);
                int byte = 216 + 8 * quad;
                int chunk = byte >> 4, off = byte & 15;
                *(u32x2*)(Xw + row * 256 + ((chunk ^ (row & 7)) << 4) + off) = u32x2{w0, w1};
            } else {
                int addr = row * 256 + ((15 ^ (row & 7)) << 4);
                *(u32x4*)(Xw + addr) = u32x4{0u, 0u, 0u, 0u};
            }
        }
    }
    __syncthreads();

    // ---------------- phase B: per-wave MLP, M=32 (2 tiles) ----------------
    const short* W1F = fr + FR_W1;
    const short* W2F = fr + FR_W2;
    const short* W3F = fr + FR_W3;

#pragma unroll 1
    for (int layer = 0; layer < 2; ++layer) {
        const short* WF = layer ? W2F : W1F;
        const float* bb = layer ? b2 : b1;

        short8 af[2][4];
#pragma unroll
        for (int m = 0; m < 2; ++m)
#pragma unroll
            for (int kt = 0; kt < 4; ++kt) {
                int row = m * 16 + lane16;
                int chunk = kt * 4 + quad;
                af[m][kt] = *(const short8*)(Xw + row * 256 + ((chunk ^ (row & 7)) << 4));
            }

#pragma unroll 1
        for (int nt = 0; nt < 8; ++nt) {
            short8 wfv[4];
#pragma unroll
            for (int kt = 0; kt < 4; ++kt)
                wfv[kt] = *(const short8*)(WF + ((kt * 8 + nt) * 64 + lane) * 8);
            f32x4 acc[2];
#pragma unroll
            for (int m = 0; m < 2; ++m) acc[m] = {0.f, 0.f, 0.f, 0.f};
#pragma unroll
            for (int m = 0; m < 2; ++m)
#pragma unroll
                for (int kt = 0; kt < 4; ++kt)
                    acc[m] = __builtin_amdgcn_mfma_f32_16x16x32_bf16(af[m][kt], wfv[kt], acc[m], 0, 0, 0);

            float bvv = bb[nt * 16 + lane16];
#pragma unroll
            for (int m = 0; m < 2; ++m) {
#pragma unroll
                for (int j = 0; j < 4; ++j) {
                    float v = acc[m][j] + bvv;
                    v = fmaxf(v, 0.01f * v);            // leaky relu
                    int row = m * 16 + quad * 4 + j;
                    int byte = (nt * 16 + lane16) * 2;
                    int chunk = byte >> 4, off = byte & 15;
                    *(short*)(Xw + row * 256 + ((chunk ^ (row & 7)) << 4) + off) =
                        (short)__builtin_bit_cast(unsigned short, (__bf16)v);
                }
            }
        }
        __syncthreads();
    }

    // ---- layer 3: 128 -> 3 (+sigmoid) ----
    {
        short8 af[2][4];
#pragma unroll
        for (int m = 0; m < 2; ++m)
#pragma unroll
            for (int kt = 0; kt < 4; ++kt) {
                int row = m * 16 + lane16;
                int chunk = kt * 4 + quad;
                af[m][kt] = *(const short8*)(Xw + row * 256 + ((chunk ^ (row & 7)) << 4));
            }
        short8 wf3[4];
#pragma unroll
        for (int kt = 0; kt < 4; ++kt)
            wf3[kt] = *(const short8*)(W3F + (kt * 64 + lane) * 8);

        f32x4 acc3[2];
#pragma unroll
        for (int m = 0; m < 2; ++m) acc3[m] = {0.f, 0.f, 0.f, 0.f};
#pragma unroll
        for (int m = 0; m < 2; ++m)
#pragma unroll
            for (int kt = 0; kt < 4; ++kt)
                acc3[m] = __builtin_amdgcn_mfma_f32_16x16x32_bf16(af[m][kt], wf3[kt], acc3[m], 0, 0, 0);

        if (lane16 < 3) {
            float bvv = b3[lane16];
#pragma unroll
            for (int m = 0; m < 2; ++m) {
#pragma unroll
                for (int j = 0; j < 4; ++j) {
                    float v = acc3[m][j] + bvv;
                    float r = 1.f / (1.f + expf(-v));   // sigmoid
                    int row = m * 16 + quad * 4 + j;
                    out[Np + (wavebase + row) * 3 + lane16] = r;
                }
            }
        }
    }
}

// ---------------- launch ----------------
extern "C" void kernel_launch(void* const* d_in, const int* in_sizes, int n_in,
                              void* d_out, int out_size, void* d_ws, size_t ws_size,
                              hipStream_t stream) {
    (void)n_in; (void)out_size; (void)ws_size;  // ws need ~424KB
    const float* xyz      = (const float*)d_in[0];
    const float* dird     = (const float*)d_in[1];
    const float* voxel    = (const float*)d_in[2];
    const float* sigma    = (const float*)d_in[3];
    const float* feature  = (const float*)d_in[4];
    const float* Bm       = (const float*)d_in[5];
    const float* W1       = (const float*)d_in[6];
    const float* b1       = (const float*)d_in[7];
    const float* W2       = (const float*)d_in[8];
    const float* b2       = (const float*)d_in[9];
    const float* W3       = (const float*)d_in[10];
    const float* b3       = (const float*)d_in[11];
    float* out = (float*)d_out;
    unsigned int* wt = (unsigned int*)d_ws;
    short* frg = (short*)d_ws + 2 * (size_t)NPAIR;   // frag region after NPAIR dwords

    const int Np = in_sizes[0] / 3;   // 524288

    prep_tables<<<(NPAIR + 255) / 256, 256, 0, stream>>>(sigma, feature, wt);
    prep_frags<<<(FR_TOT + 255) / 256, 256, 0, stream>>>(Bm, W1, W2, W3, frg);
    tensorf_main<<<Np / 64, 128, 0, stream>>>(xyz, dird, voxel, b1, b2, b3, wt, frg, out, Np);
}